// Round 22
// baseline (118.312 us; speedup 1.0000x reference)
//
#include <hip/hip_runtime.h>

typedef __bf16 bf16_t;
typedef __attribute__((ext_vector_type(2))) __bf16 bf16x2;
typedef __attribute__((ext_vector_type(4))) __bf16 bf16x4;
typedef __attribute__((ext_vector_type(8))) __bf16 bf16x8;
typedef __attribute__((ext_vector_type(4))) float f32x4;
typedef __attribute__((ext_vector_type(16))) float f32x16;

#define MFMA16(a, b, c) __builtin_amdgcn_mfma_f32_16x16x32_bf16((a), (b), (c), 0, 0, 0)
#define MFMA32(a, b, c) __builtin_amdgcn_mfma_f32_32x32x16_bf16((a), (b), (c), 0, 0, 0)
#define AS1 __attribute__((address_space(1)))
#define AS3 __attribute__((address_space(3)))

// Problem: B=8 S=1024 D=768 H=16 Dh=64 OD=1024, M = B*S = 8192
static constexpr unsigned WT_OFF = 12582912u;                   // wT bf16 (3,1024,768)
static constexpr unsigned Q_OFF  = WT_OFF + 4718592u;           // Qf bf16: 16,777,216
static constexpr unsigned K_OFF  = Q_OFF + 16777216u;
static constexpr unsigned VT_OFF = K_OFF + 16777216u;           // end = 67,633,152

// ---------------- cast kernel: WEIGHTS ONLY (x fused into proj) --------------
__global__ __launch_bounds__(256) void cast_kernel(const float* __restrict__ qw,
                                                   const float* __restrict__ kw,
                                                   const float* __restrict__ vw,
                                                   bf16_t* __restrict__ wT) {
    unsigned t = blockIdx.x * 256u + threadIdx.x;   // 2304 blocks
    unsigned w  = t / 196608u;
    unsigned r  = t % 196608u;
    unsigned n  = r % 1024u;
    unsigned k4 = r / 1024u;
    const float* src = (w == 0u) ? qw : (w == 1u) ? kw : vw;
    float s = (w == 0u) ? 0.18033688011112043f : 1.0f;   // 0.125*log2(e) folded for exp2
    bf16x4 o;
#pragma unroll
    for (int i = 0; i < 4; ++i) o[i] = (bf16_t)(src[(k4 * 4u + i) * 1024u + n] * s);
    *(bf16x4*)&wT[(w * 1024u + n) * 768u + k4 * 4u] = o;
}

// ---------------- fused cast+QKV projection GEMM -----------------------------
// A staged from fp32 x DIRECTLY: global float4 -> regs -> bf16 cvt -> swizzled
// ds_write (write-side swizzle ga^((row>>1)&3) composes with read-side to
// identity). B keeps gload_lds. Single A-reg buffer (32 VGPR), depth-1
// pipeline: load(p+2) latency covered by a full phase. Eliminates the 25MB
// xb round-trip + one kernel.
__global__ __launch_bounds__(256, 2) void proj_kernel(const float* __restrict__ xf,
                                                      const bf16_t* __restrict__ wT,
                                                      bf16_t* __restrict__ q,
                                                      bf16_t* __restrict__ k,
                                                      bf16_t* __restrict__ vt) {
    __shared__ __align__(16) char smem[73728];          // 72KB: As 48KB | Bs 24KB
    bf16_t* Asp = (bf16_t*)smem;                        // 3 slots x 8192 elems
    bf16_t* Bsp = (bf16_t*)(smem + 49152);              // 3 slots x 4096 elems
    const int id = blockIdx.x;
    const int work = (id & 7) * 96 + (id >> 3);         // bijective, 768 = 8*96
    const int nb = work & 7, mb = (work >> 3) & 31, wsel = work >> 8;
    const int t = threadIdx.x;
    const int w = t >> 6, l = t & 63;
    const int lo = l & 15, hi = l >> 4;
    const int wm = w >> 1, wn = w & 1;                  // 2x2 waves; per-wave 128x64
    const float*  abase = xf + (unsigned)(mb * 256) * 768u;
    const bf16_t* bbase = wT + wsel * (1024 * 768) + nb * 128 * 768;
    const int srow = w * 16 + (l >> 2);
    const int gsrc = ((l & 3) ^ ((l >> 3) & 3)) * 8;    // B pre-swizzled source granule
    const int rg = (hi ^ ((lo >> 1) & 3)) << 3;         // read-side granule
    // A staging: thread covers rows j*64 + (t>>2), granule ga = t&3 (8 cols)
    const int arow0 = t >> 2;
    const int ga8 = (t & 3) * 8;
    const int gaw = (((t & 3) ^ ((t >> 3) & 3)) << 3);  // write-side swizzled granule

#define STAGE_B(slot, p)                                                            \
    do {                                                                            \
        const int ko_ = (p) * 32 + gsrc;                                            \
        _Pragma("unroll")                                                           \
        for (int g_ = 0; g_ < 2; ++g_)                                              \
            __builtin_amdgcn_global_load_lds(                                       \
                (const AS1 void*)(bbase + (g_ * 64 + srow) * 768 + ko_),            \
                (AS3 void*)(Bsp + (slot) * 4096 + g_ * 2048 + w * 512), 16, 0, 0);  \
    } while (0)

    float4 aBuf[8];
#define LOADA(p)                                                                  \
    do {                                                                          \
        _Pragma("unroll")                                                         \
        for (int j_ = 0; j_ < 4; ++j_) {                                          \
            const float* rp_ = abase + (unsigned)(j_ * 64 + arow0) * 768u + (p) * 32 + ga8; \
            aBuf[2 * j_]     = *(const float4*)rp_;                               \
            aBuf[2 * j_ + 1] = *(const float4*)(rp_ + 4);                         \
        }                                                                         \
    } while (0)

#define CVTWRITE(slotv)                                                           \
    do {                                                                          \
        _Pragma("unroll")                                                         \
        for (int j_ = 0; j_ < 4; ++j_) {                                          \
            const int r_ = j_ * 64 + arow0;                                       \
            bf16x8 v_;                                                            \
            v_[0] = (bf16_t)aBuf[2 * j_].x;     v_[1] = (bf16_t)aBuf[2 * j_].y;   \
            v_[2] = (bf16_t)aBuf[2 * j_].z;     v_[3] = (bf16_t)aBuf[2 * j_].w;   \
            v_[4] = (bf16_t)aBuf[2 * j_ + 1].x; v_[5] = (bf16_t)aBuf[2 * j_ + 1].y; \
            v_[6] = (bf16_t)aBuf[2 * j_ + 1].z; v_[7] = (bf16_t)aBuf[2 * j_ + 1].w; \
            *(bf16x8*)&Asp[(slotv) * 8192 + r_ * 32 + gaw] = v_;                  \
        }                                                                         \
    } while (0)

    bf16x8 af[8], bfr[4];
#define DSREAD(slotv)                                                             \
    do {                                                                          \
        const bf16_t* Ab_ = Asp + (slotv) * 8192;                                 \
        const bf16_t* Bb_ = Bsp + (slotv) * 4096;                                 \
        _Pragma("unroll") for (int m_ = 0; m_ < 8; ++m_)                          \
            af[m_] = *(const bf16x8*)&Ab_[(wm * 128 + m_ * 16 + lo) * 32 + rg];   \
        _Pragma("unroll") for (int n_ = 0; n_ < 4; ++n_)                          \
            bfr[n_] = *(const bf16x8*)&Bb_[(wn * 64 + n_ * 16 + lo) * 32 + rg];   \
    } while (0)

#define DOMFMA()                                                                  \
    do {                                                                          \
        __builtin_amdgcn_s_setprio(1);                                            \
        _Pragma("unroll") for (int m_ = 0; m_ < 8; ++m_)                          \
        _Pragma("unroll") for (int n_ = 0; n_ < 4; ++n_)                          \
            acc[m_][n_] = MFMA16(af[m_], bfr[n_], acc[m_][n_]);                   \
        __builtin_amdgcn_s_setprio(0);                                            \
    } while (0)

    f32x4 acc[8][4];
#pragma unroll
    for (int m = 0; m < 8; ++m)
#pragma unroll
        for (int n = 0; n < 4; ++n)
#pragma unroll
            for (int i = 0; i < 4; ++i) acc[m][n][i] = 0.f;

    // prologue: tile0 A->regs->LDS, tile1 A in flight; B0,B1 staged
    LOADA(0);                        // 8 vm
    STAGE_B(0, 0);                   // 2 vm
    asm volatile("s_waitcnt vmcnt(2)" ::: "memory");   // A(0) landed (B0 may be in flight)
    CVTWRITE(0);
    LOADA(1);                        // aBuf freed by CVTWRITE
    STAGE_B(1, 1);
    asm volatile("s_waitcnt vmcnt(10)" ::: "memory");  // B0 landed (A1,B1 in flight)
    asm volatile("s_waitcnt lgkmcnt(0)" ::: "memory"); // A0 ds_writes done
    __builtin_amdgcn_s_barrier();                      // publish tile 0

    int slot = 0;
    for (int p = 0; p < 22; ++p) {
        DSREAD(slot);                                      // tile p published
        asm volatile("s_waitcnt vmcnt(0)" ::: "memory");   // A(p+1) regs + B(p+1) landed
        const int s1 = (slot + 1 >= 3) ? slot - 2 : slot + 1;
        CVTWRITE(s1);                                      // A(p+1) -> slot p+1 (freed p-2)
        const int s2 = (slot + 2 >= 3) ? slot - 1 : slot + 2;
        STAGE_B(s2, p + 2);                                // slot p-1: consumed at p-1
        LOADA(p + 2);                                      // aBuf freed by CVTWRITE
        DOMFMA();                                          // consumes DSREAD(p)
        asm volatile("s_waitcnt lgkmcnt(0)" ::: "memory"); // my ds_writes drained
        __builtin_amdgcn_s_barrier();                      // publish tile p+1
        slot = s1;
    }
    // tail: p = 22, 23 (tile 23 regs/B already in flight; no new issues)
    DSREAD(1);                                             // 22 % 3
    asm volatile("s_waitcnt vmcnt(0)" ::: "memory");       // A(23) regs + B(23) landed
    CVTWRITE(2);                                           // tile 23 -> slot 2
    DOMFMA();
    asm volatile("s_waitcnt lgkmcnt(0)" ::: "memory");
    __builtin_amdgcn_s_barrier();                          // publish tile 23
    DSREAD(2);
    DOMFMA();
#undef STAGE_B
#undef LOADA
#undef CVTWRITE
#undef DSREAD
#undef DOMFMA

    // ---- epilogue: LDS transpose -> 16 coalesced 1KB chunk stores per wave ----
    asm volatile("s_waitcnt lgkmcnt(0)" ::: "memory");
    __builtin_amdgcn_s_barrier();            // all waves past final DSREAD; LDS free
    bf16_t* ep = (bf16_t*)(smem + (unsigned)w * 16384u);   // per-wave 16KB carve
    if (wsel != 2) {
        const int lA = ((lo >> 3) & 1) * 32 + hi * 4;
#pragma unroll
        for (int m = 0; m < 8; ++m)
#pragma unroll
            for (int n = 0; n < 4; ++n)
#pragma unroll
                for (int r = 0; r < 4; ++r)
                    ep[((m >> 1) * 4 + n) * 512 + (lA + (m & 1) * 16 + r) * 8 + (lo & 7)] =
                        (bf16_t)acc[m][n][r];
    } else {
#pragma unroll
        for (int m = 0; m < 8; ++m)
#pragma unroll
            for (int n = 0; n < 4; ++n)
#pragma unroll
                for (int r = 0; r < 4; ++r) {
                    const int sr = hi * 4 + r;   // ss&15
                    ep[((m >> 2) * 8 + (m & 3) * 2 + (n >> 1)) * 512
                       + (((sr >> 3) & 1) * 32 + (n & 1) * 16 + lo) * 8 + (sr & 7)] =
                        (bf16_t)acc[m][n][r];
                }
    }
    asm volatile("s_waitcnt lgkmcnt(0)" ::: "memory");
    __builtin_amdgcn_sched_barrier(0);       // rule #18: pin reads after the wait
    const unsigned headoff = (unsigned)((mb >> 2) * 16 + nb * 2 + wn) << 16;
    bf16_t* dst = (wsel == 0) ? q : (wsel == 1) ? k : vt;
#pragma unroll
    for (int c = 0; c < 16; ++c) {
        unsigned gchunk;
        if (wsel == 0) {
            const int m2 = c >> 2, sq = c & 3;
            gchunk = (unsigned)(((mb & 3) * 8 + wm * 4 + m2) * 4 + sq);
        } else if (wsel == 1) {
            const int m2 = c >> 2, sq = c & 3;
            gchunk = (unsigned)(((mb & 3) * 4 + wm * 2 + (m2 >> 1)) * 8 + sq * 2 + (m2 & 1));
        } else {
            const int ktl = c >> 3, S = (c >> 1) & 3, hl = c & 1;
            gchunk = (unsigned)(((mb & 3) * 4 + wm * 2 + ktl) * 8 + S * 2 + hl);
        }
        *(bf16x8*)&dst[headoff + gchunk * 512u + l * 8] = *(const bf16x8*)&ep[c * 512 + l * 8];
    }
}

// ---------------- flash attention (r18 exact — best measured, 48.4us) --------
__global__ __launch_bounds__(512) void attn_kernel(const bf16_t* __restrict__ Q,
                                                   const bf16_t* __restrict__ K,
                                                   const bf16_t* __restrict__ Vt,
                                                   float* __restrict__ out) {
    __shared__ __align__(16) char asmem[65536];    // kv[2][2 tiles x 8192]; reused as olds
    bf16_t* kvp = (bf16_t*)asmem;
    const int w = threadIdx.x >> 6, l = threadIdx.x & 63;   // w: 0..7
    const int hb = blockIdx.x & 127;             // head: fixes XCD by hb%8
    const int qblk = blockIdx.x >> 7;            // 0..3
    const int qw = qblk * 8 + w;                 // q-tile 0..31 within head
    const int b = hb >> 4, h = hb & 15;
    const int ln = l & 31, hi = l >> 5;
    const unsigned bh = (unsigned)hb << 16;
    const bf16_t* Qh = Q + bh;
    const bf16_t* Kh = K + bh;
    const bf16_t* Vh = Vt + bh;
    const int l8 = l * 8;

#define ASTAGE2(slot, pair)                                                      \
    do {                                                                         \
        _Pragma("unroll")                                                        \
        for (int tt = 0; tt < 2; ++tt) {                                         \
            const bf16_t* ks_ = Kh + ((pair) * 2 + tt) * 4096;                   \
            const bf16_t* vs_ = Vh + ((pair) * 2 + tt) * 4096;                   \
            bf16_t* dst_ = kvp + (slot) * 16384 + tt * 8192;                     \
            __builtin_amdgcn_global_load_lds(                                    \
                (const AS1 void*)(ks_ + w * 512 + l8),                           \
                (AS3 void*)(dst_ + w * 512), 16, 0, 0);                          \
            __builtin_amdgcn_global_load_lds(                                    \
                (const AS1 void*)(vs_ + w * 512 + l8),                           \
                (AS3 void*)(dst_ + 4096 + w * 512), 16, 0, 0);                   \
        }                                                                        \
    } while (0)

    bf16x8 qf[4];
#pragma unroll
    for (int s = 0; s < 4; ++s)
        qf[s] = *(const bf16x8*)&Qh[(qw * 4 + s) * 512 + l8];

    f32x16 of0, of1;
#pragma unroll
    for (int r = 0; r < 16; ++r) { of0[r] = 0.f; of1[r] = 0.f; }
    float sacc[16];
#pragma unroll
    for (int r = 0; r < 16; ++r) sacc[r] = 0.f;

#define ATILE_QK(Kt, sc0, sc1)                                                   \
    do {                                                                         \
        _Pragma("unroll") for (int r = 0; r < 16; ++r) { sc0[r] = 0.f; sc1[r] = 0.f; } \
        __builtin_amdgcn_s_setprio(1);                                           \
        _Pragma("unroll") for (int s = 0; s < 4; ++s) {                          \
            bf16x8 k0 = *(const bf16x8*)&(Kt)[(s * 2 + 0) * 512 + l8];           \
            bf16x8 k1 = *(const bf16x8*)&(Kt)[(s * 2 + 1) * 512 + l8];           \
            sc0 = MFMA32(k0, qf[s], sc0);                                        \
            sc1 = MFMA32(k1, qf[s], sc1);                                        \
        }                                                                        \
        __builtin_amdgcn_s_setprio(0);                                           \
    } while (0)

#define ATILE_SM(sc0, sc1, own)                                                  \
    do {                                                                         \
        float p0[16], p1[16];                                                    \
        _Pragma("unroll") for (int r = 0; r < 16; ++r) {                         \
            p0[r] = __builtin_amdgcn_exp2f(sc0[r]);                              \
            p1[r] = __builtin_amdgcn_exp2f(sc1[r]);                              \
        }                                                                        \
        _Pragma("unroll") for (int r = 0; r < 16; ++r) sacc[r] += p0[r] + p1[r]; \
        _Pragma("unroll") for (int t2 = 0; t2 < 8; ++t2) {                       \
            bf16x2 v0; v0[0] = (bf16_t)p0[2 * t2]; v0[1] = (bf16_t)p0[2 * t2 + 1]; \
            bf16x2 v1; v1[0] = (bf16_t)p1[2 * t2]; v1[1] = (bf16_t)p1[2 * t2 + 1]; \
            own[t2]     = __builtin_bit_cast(unsigned, v0);                      \
            own[8 + t2] = __builtin_bit_cast(unsigned, v1);                      \
        }                                                                        \
    } while (0)

#define ATILE_PV(Vtt, own)                                                       \
    do {                                                                         \
        bf16x8 vf0[4], vf1[4];                                                   \
        _Pragma("unroll") for (int S = 0; S < 4; ++S) {                          \
            vf0[S] = *(const bf16x8*)&(Vtt)[(S * 2 + 0) * 512 + l8];             \
            vf1[S] = *(const bf16x8*)&(Vtt)[(S * 2 + 1) * 512 + l8];             \
        }                                                                        \
        __builtin_amdgcn_s_setprio(1);                                           \
        _Pragma("unroll") for (int S = 0; S < 4; ++S) {                          \
            const int b0 = (S >> 1) * 8 + (S & 1) * 4;                           \
            unsigned w0 = own[b0 + 0], w2 = own[b0 + 2];                         \
            unsigned w1 = own[b0 + 1], w3 = own[b0 + 3];                         \
            asm("v_permlane32_swap_b32 %0, %1" : "+v"(w0), "+v"(w2));            \
            asm("v_permlane32_swap_b32 %0, %1" : "+v"(w1), "+v"(w3));            \
            union { unsigned u[4]; bf16x8 v; } pb;                               \
            pb.u[0] = w0; pb.u[1] = w1; pb.u[2] = w2; pb.u[3] = w3;              \
            of0 = MFMA32(vf0[S], pb.v, of0);                                     \
            of1 = MFMA32(vf1[S], pb.v, of1);                                     \
        }                                                                        \
        __builtin_amdgcn_s_setprio(0);                                           \
    } while (0)

#define ACOMPUTE2(cur)                                                           \
    do {                                                                         \
        const bf16_t* KtA = kvp + (cur) * 16384;                                 \
        const bf16_t* VtA = KtA + 4096;                                          \
        const bf16_t* KtB = KtA + 8192;                                          \
        const bf16_t* VtB = KtA + 12288;                                         \
        f32x16 scA0, scA1;                                                       \
        ATILE_QK(KtA, scA0, scA1);                                               \
        unsigned ownA[16];                                                       \
        ATILE_SM(scA0, scA1, ownA);                                              \
        f32x16 scB0, scB1;                                                       \
        ATILE_QK(KtB, scB0, scB1);                                               \
        ATILE_PV(VtA, ownA);                                                     \
        unsigned ownB[16];                                                       \
        ATILE_SM(scB0, scB1, ownB);                                              \
        ATILE_PV(VtB, ownB);                                                     \
    } while (0)

    ASTAGE2(0, 0);
    ASTAGE2(1, 1);
    asm volatile("s_waitcnt vmcnt(4)" ::: "memory");
    __builtin_amdgcn_s_barrier();

    for (int p = 0; p < 6; ++p) {
        const int cur = p & 1;
        ACOMPUTE2(cur);
        asm volatile("s_waitcnt lgkmcnt(0)" ::: "memory");
        __builtin_amdgcn_s_barrier();
        ASTAGE2(cur, p + 2);
        asm volatile("s_waitcnt vmcnt(4)" ::: "memory");
        __builtin_amdgcn_s_barrier();
    }
    ACOMPUTE2(0);
    asm volatile("s_waitcnt lgkmcnt(0)" ::: "memory");
    __builtin_amdgcn_s_barrier();
    asm volatile("s_waitcnt vmcnt(0)" ::: "memory");
    __builtin_amdgcn_s_barrier();
    ACOMPUTE2(1);
#undef ASTAGE2
#undef ACOMPUTE2
#undef ATILE_QK
#undef ATILE_SM
#undef ATILE_PV

    asm volatile("s_waitcnt lgkmcnt(0)" ::: "memory");
    __builtin_amdgcn_s_barrier();

#pragma unroll
    for (int st = 8; st >= 1; st >>= 1)
#pragma unroll
        for (int r = 0; r < 8; ++r)
            if (r < st) sacc[r] += sacc[r + st];
    float ltot = sacc[0] + __shfl_xor(sacc[0], 32);
    float inv = 1.f / ltot;
    float* ol = (float*)asmem + (unsigned)w * 2048u;   // per-wave 8KB carve
#pragma unroll
    for (int r = 0; r < 16; ++r) {
        int d = (r & 3) + 8 * (r >> 2) + 4 * hi;
        int d2 = 32 + d;
        ol[d * 32 + (ln ^ (d & 31))]    = of0[r] * inv;
        ol[d2 * 32 + (ln ^ (d2 & 31))]  = of1[r] * inv;
    }
    const unsigned obase = (unsigned)(b * 1024 + qw * 32) * 1024u + h * 64 + l;
#pragma unroll 8
    for (int qq = 0; qq < 32; ++qq)
        out[obase + qq * 1024u] = ol[l * 32 + (qq ^ (l & 31))];
}

extern "C" void kernel_launch(void* const* d_in, const int* in_sizes, int n_in,
                              void* d_out, int out_size, void* d_ws, size_t ws_size,
                              hipStream_t stream) {
    const float* x  = (const float*)d_in[0];
    const float* qw = (const float*)d_in[1];
    const float* kw = (const float*)d_in[2];
    const float* vw = (const float*)d_in[3];
    float* out = (float*)d_out;
    char* ws = (char*)d_ws;
    if (ws_size < 67633152u) return;

    bf16_t* wT = (bf16_t*)(ws + WT_OFF);
    bf16_t* Qb = (bf16_t*)(ws + Q_OFF);
    bf16_t* Kb = (bf16_t*)(ws + K_OFF);
    bf16_t* Vt = (bf16_t*)(ws + VT_OFF);

    cast_kernel<<<2304, 256, 0, stream>>>(qw, kw, vw, wT);
    proj_kernel<<<768, 256, 0, stream>>>(x, wT, Qb, Kb, Vt);
    attn_kernel<<<512, 512, 0, stream>>>(Qb, Kb, Vt, out);
}

// Round 23
// 103.255 us; speedup vs baseline: 1.1458x; 1.1458x over previous
//
#include <hip/hip_runtime.h>

typedef __bf16 bf16_t;
typedef __attribute__((ext_vector_type(2))) __bf16 bf16x2;
typedef __attribute__((ext_vector_type(4))) __bf16 bf16x4;
typedef __attribute__((ext_vector_type(8))) __bf16 bf16x8;
typedef __attribute__((ext_vector_type(4))) float f32x4;
typedef __attribute__((ext_vector_type(16))) float f32x16;

#define MFMA16(a, b, c) __builtin_amdgcn_mfma_f32_16x16x32_bf16((a), (b), (c), 0, 0, 0)
#define MFMA32(a, b, c) __builtin_amdgcn_mfma_f32_32x32x16_bf16((a), (b), (c), 0, 0, 0)
#define AS1 __attribute__((address_space(1)))
#define AS3 __attribute__((address_space(3)))

// Problem: B=8 S=1024 D=768 H=16 Dh=64 OD=1024, M = B*S = 8192
static constexpr unsigned XB_OFF = 0u;                          // x bf16 row-major: 12,582,912
static constexpr unsigned WT_OFF = 12582912u;                   // wT bf16 (3,1024,768): 4,718,592
static constexpr unsigned Q_OFF  = WT_OFF + 4718592u;           // Qf bf16: 16,777,216
static constexpr unsigned K_OFF  = Q_OFF + 16777216u;
static constexpr unsigned VT_OFF = K_OFF + 16777216u;           // end = 67,633,152

// ---------------- merged cast kernel ----------------
__global__ __launch_bounds__(256) void cast_kernel(const float4* __restrict__ x4,
                                                   bf16x4* __restrict__ out4,
                                                   const float* __restrict__ qw,
                                                   const float* __restrict__ kw,
                                                   const float* __restrict__ vw,
                                                   bf16_t* __restrict__ wT) {
    if (blockIdx.x < 6144u) {
        unsigned i = blockIdx.x * 256u + threadIdx.x;
        float4 v = x4[i];
        bf16x4 o;
        o[0] = (bf16_t)v.x; o[1] = (bf16_t)v.y; o[2] = (bf16_t)v.z; o[3] = (bf16_t)v.w;
        out4[i] = o;
    } else {
        unsigned t = (blockIdx.x - 6144u) * 256u + threadIdx.x;
        unsigned w  = t / 196608u;
        unsigned r  = t % 196608u;
        unsigned n  = r % 1024u;
        unsigned k4 = r / 1024u;
        const float* src = (w == 0u) ? qw : (w == 1u) ? kw : vw;
        float s = (w == 0u) ? 0.18033688011112043f : 1.0f;   // 0.125*log2(e) folded for exp2
        bf16x4 o;
#pragma unroll
        for (int i = 0; i < 4; ++i) o[i] = (bf16_t)(src[(k4 * 4u + i) * 1024u + n] * s);
        *(bf16x4*)&wT[(w * 1024u + n) * 768u + k4 * 4u] = o;
    }
}

// ---------------- fused QKV projection GEMM (r19 exact — best measured) ------
// 3 slots, 72KB, 2 blocks/CU, single-barrier consumption-ordered phases,
// coalesced LDS-transpose epilogue.
__global__ __launch_bounds__(256, 2) void proj_kernel(const bf16_t* __restrict__ xb,
                                                      const bf16_t* __restrict__ wT,
                                                      bf16_t* __restrict__ q,
                                                      bf16_t* __restrict__ k,
                                                      bf16_t* __restrict__ vt) {
    __shared__ __align__(16) char smem[73728];          // 72KB: As 48KB | Bs 24KB
    bf16_t* Asp = (bf16_t*)smem;                        // 3 slots x 8192 elems
    bf16_t* Bsp = (bf16_t*)(smem + 49152);              // 3 slots x 4096 elems
    const int id = blockIdx.x;
    const int work = (id & 7) * 96 + (id >> 3);         // bijective, 768 = 8*96
    const int nb = work & 7, mb = (work >> 3) & 31, wsel = work >> 8;
    const int t = threadIdx.x;
    const int w = t >> 6, l = t & 63;
    const int lo = l & 15, hi = l >> 4;
    const int wm = w >> 1, wn = w & 1;                  // 2x2 waves; per-wave 128x64
    const bf16_t* abase = xb + mb * 256 * 768;
    const bf16_t* bbase = wT + wsel * (1024 * 768) + nb * 128 * 768;
    const int srow = w * 16 + (l >> 2);
    const int gsrc = ((l & 3) ^ ((l >> 3) & 3)) * 8;
    const int rg = (hi ^ ((lo >> 1) & 3)) << 3;         // read-side granule

#define STAGE(slot, p)                                                              \
    do {                                                                            \
        const int ko_ = (p) * 32 + gsrc;                                            \
        _Pragma("unroll")                                                           \
        for (int g_ = 0; g_ < 4; ++g_)                                              \
            __builtin_amdgcn_global_load_lds(                                       \
                (const AS1 void*)(abase + (g_ * 64 + srow) * 768 + ko_),            \
                (AS3 void*)(Asp + (slot) * 8192 + g_ * 2048 + w * 512), 16, 0, 0);  \
        _Pragma("unroll")                                                           \
        for (int g_ = 0; g_ < 2; ++g_)                                              \
            __builtin_amdgcn_global_load_lds(                                       \
                (const AS1 void*)(bbase + (g_ * 64 + srow) * 768 + ko_),            \
                (AS3 void*)(Bsp + (slot) * 4096 + g_ * 2048 + w * 512), 16, 0, 0);  \
    } while (0)

    bf16x8 af[8], bfr[4];
#define DSREAD(slotv)                                                             \
    do {                                                                          \
        const bf16_t* Ab_ = Asp + (slotv) * 8192;                                 \
        const bf16_t* Bb_ = Bsp + (slotv) * 4096;                                 \
        _Pragma("unroll") for (int m_ = 0; m_ < 8; ++m_)                          \
            af[m_] = *(const bf16x8*)&Ab_[(wm * 128 + m_ * 16 + lo) * 32 + rg];   \
        _Pragma("unroll") for (int n_ = 0; n_ < 4; ++n_)                          \
            bfr[n_] = *(const bf16x8*)&Bb_[(wn * 64 + n_ * 16 + lo) * 32 + rg];   \
    } while (0)

#define DOMFMA()                                                                  \
    do {                                                                          \
        __builtin_amdgcn_s_setprio(1);                                            \
        _Pragma("unroll") for (int m_ = 0; m_ < 8; ++m_)                          \
        _Pragma("unroll") for (int n_ = 0; n_ < 4; ++n_)                          \
            acc[m_][n_] = MFMA16(af[m_], bfr[n_], acc[m_][n_]);                   \
        __builtin_amdgcn_s_setprio(0);                                            \
    } while (0)

    f32x4 acc[8][4];
#pragma unroll
    for (int m = 0; m < 8; ++m)
#pragma unroll
        for (int n = 0; n < 4; ++n)
#pragma unroll
            for (int i = 0; i < 4; ++i) acc[m][n][i] = 0.f;

    STAGE(0, 0);
    STAGE(1, 1);
    asm volatile("s_waitcnt vmcnt(6)" ::: "memory");
    __builtin_amdgcn_s_barrier();

    int slot = 0;
    for (int p = 0; p < 22; ++p) {
        DSREAD(slot);                                      // slot p published
        const int s2 = (slot + 2 >= 3) ? slot - 1 : slot + 2;
        STAGE(s2, p + 2);                                  // slot p-1: reads consumed at p-1
        DOMFMA();                                          // consumes DSREAD(p)
        asm volatile("s_waitcnt vmcnt(6)" ::: "memory");   // stage(p+1) landed
        __builtin_amdgcn_s_barrier();                      // publish slot p+1
        slot = (slot + 1 >= 3) ? 0 : slot + 1;
    }
    // tail: p = 22, 23
    DSREAD(1);
    DOMFMA();
    asm volatile("s_waitcnt vmcnt(0)" ::: "memory");       // stage(23) landed
    __builtin_amdgcn_s_barrier();
    DSREAD(2);
    DOMFMA();
#undef STAGE
#undef DSREAD
#undef DOMFMA

    // ---- epilogue: LDS transpose -> 16 coalesced 1KB chunk stores per wave ----
    asm volatile("s_waitcnt lgkmcnt(0)" ::: "memory");
    __builtin_amdgcn_s_barrier();            // all waves past final DSREAD; LDS free
    bf16_t* ep = (bf16_t*)(smem + (unsigned)w * 16384u);   // per-wave 16KB carve
    if (wsel != 2) {
        const int lA = ((lo >> 3) & 1) * 32 + hi * 4;
#pragma unroll
        for (int m = 0; m < 8; ++m)
#pragma unroll
            for (int n = 0; n < 4; ++n)
#pragma unroll
                for (int r = 0; r < 4; ++r)
                    ep[((m >> 1) * 4 + n) * 512 + (lA + (m & 1) * 16 + r) * 8 + (lo & 7)] =
                        (bf16_t)acc[m][n][r];
    } else {
#pragma unroll
        for (int m = 0; m < 8; ++m)
#pragma unroll
            for (int n = 0; n < 4; ++n)
#pragma unroll
                for (int r = 0; r < 4; ++r) {
                    const int sr = hi * 4 + r;   // ss&15
                    ep[((m >> 2) * 8 + (m & 3) * 2 + (n >> 1)) * 512
                       + (((sr >> 3) & 1) * 32 + (n & 1) * 16 + lo) * 8 + (sr & 7)] =
                        (bf16_t)acc[m][n][r];
                }
    }
    asm volatile("s_waitcnt lgkmcnt(0)" ::: "memory");
    __builtin_amdgcn_sched_barrier(0);       // rule #18: pin reads after the wait
    const unsigned headoff = (unsigned)((mb >> 2) * 16 + nb * 2 + wn) << 16;
    bf16_t* dst = (wsel == 0) ? q : (wsel == 1) ? k : vt;
#pragma unroll
    for (int c = 0; c < 16; ++c) {
        unsigned gchunk;
        if (wsel == 0) {
            const int m2 = c >> 2, sq = c & 3;
            gchunk = (unsigned)(((mb & 3) * 8 + wm * 4 + m2) * 4 + sq);
        } else if (wsel == 1) {
            const int m2 = c >> 2, sq = c & 3;
            gchunk = (unsigned)(((mb & 3) * 4 + wm * 2 + (m2 >> 1)) * 8 + sq * 2 + (m2 & 1));
        } else {
            const int ktl = c >> 3, S = (c >> 1) & 3, hl = c & 1;
            gchunk = (unsigned)(((mb & 3) * 4 + wm * 2 + ktl) * 8 + S * 2 + hl);
        }
        *(bf16x8*)&dst[headoff + gchunk * 512u + l * 8] = *(const bf16x8*)&ep[c * 512 + l * 8];
    }
}

// ---------------- flash attention (r18 exact — best measured, 48.4us) --------
// 8 waves share staged K/V; 2 pair-slots (2 kt tiles each), LDS 64KB
// (2 blocks/CU, olds aliased). 2-tile ILP phase order + deferred lsum.
__global__ __launch_bounds__(512) void attn_kernel(const bf16_t* __restrict__ Q,
                                                   const bf16_t* __restrict__ K,
                                                   const bf16_t* __restrict__ Vt,
                                                   float* __restrict__ out) {
    __shared__ __align__(16) char asmem[65536];    // kv[2][2 tiles x 8192]; reused as olds
    bf16_t* kvp = (bf16_t*)asmem;
    const int w = threadIdx.x >> 6, l = threadIdx.x & 63;   // w: 0..7
    const int hb = blockIdx.x & 127;             // head: fixes XCD by hb%8
    const int qblk = blockIdx.x >> 7;            // 0..3
    const int qw = qblk * 8 + w;                 // q-tile 0..31 within head
    const int b = hb >> 4, h = hb & 15;
    const int ln = l & 31, hi = l >> 5;
    const unsigned bh = (unsigned)hb << 16;
    const bf16_t* Qh = Q + bh;
    const bf16_t* Kh = K + bh;
    const bf16_t* Vh = Vt + bh;
    const int l8 = l * 8;

#define ASTAGE2(slot, pair)                                                      \
    do {                                                                         \
        _Pragma("unroll")                                                        \
        for (int tt = 0; tt < 2; ++tt) {                                         \
            const bf16_t* ks_ = Kh + ((pair) * 2 + tt) * 4096;                   \
            const bf16_t* vs_ = Vh + ((pair) * 2 + tt) * 4096;                   \
            bf16_t* dst_ = kvp + (slot) * 16384 + tt * 8192;                     \
            __builtin_amdgcn_global_load_lds(                                    \
                (const AS1 void*)(ks_ + w * 512 + l8),                           \
                (AS3 void*)(dst_ + w * 512), 16, 0, 0);                          \
            __builtin_amdgcn_global_load_lds(                                    \
                (const AS1 void*)(vs_ + w * 512 + l8),                           \
                (AS3 void*)(dst_ + 4096 + w * 512), 16, 0, 0);                   \
        }                                                                        \
    } while (0)

    bf16x8 qf[4];
#pragma unroll
    for (int s = 0; s < 4; ++s)
        qf[s] = *(const bf16x8*)&Qh[(qw * 4 + s) * 512 + l8];

    f32x16 of0, of1;
#pragma unroll
    for (int r = 0; r < 16; ++r) { of0[r] = 0.f; of1[r] = 0.f; }
    float sacc[16];
#pragma unroll
    for (int r = 0; r < 16; ++r) sacc[r] = 0.f;

#define ATILE_QK(Kt, sc0, sc1)                                                   \
    do {                                                                         \
        _Pragma("unroll") for (int r = 0; r < 16; ++r) { sc0[r] = 0.f; sc1[r] = 0.f; } \
        __builtin_amdgcn_s_setprio(1);                                           \
        _Pragma("unroll") for (int s = 0; s < 4; ++s) {                          \
            bf16x8 k0 = *(const bf16x8*)&(Kt)[(s * 2 + 0) * 512 + l8];           \
            bf16x8 k1 = *(const bf16x8*)&(Kt)[(s * 2 + 1) * 512 + l8];           \
            sc0 = MFMA32(k0, qf[s], sc0);                                        \
            sc1 = MFMA32(k1, qf[s], sc1);                                        \
        }                                                                        \
        __builtin_amdgcn_s_setprio(0);                                           \
    } while (0)

#define ATILE_SM(sc0, sc1, own)                                                  \
    do {                                                                         \
        float p0[16], p1[16];                                                    \
        _Pragma("unroll") for (int r = 0; r < 16; ++r) {                         \
            p0[r] = __builtin_amdgcn_exp2f(sc0[r]);                              \
            p1[r] = __builtin_amdgcn_exp2f(sc1[r]);                              \
        }                                                                        \
        _Pragma("unroll") for (int r = 0; r < 16; ++r) sacc[r] += p0[r] + p1[r]; \
        _Pragma("unroll") for (int t2 = 0; t2 < 8; ++t2) {                       \
            bf16x2 v0; v0[0] = (bf16_t)p0[2 * t2]; v0[1] = (bf16_t)p0[2 * t2 + 1]; \
            bf16x2 v1; v1[0] = (bf16_t)p1[2 * t2]; v1[1] = (bf16_t)p1[2 * t2 + 1]; \
            own[t2]     = __builtin_bit_cast(unsigned, v0);                      \
            own[8 + t2] = __builtin_bit_cast(unsigned, v1);                      \
        }                                                                        \
    } while (0)

#define ATILE_PV(Vtt, own)                                                       \
    do {                                                                         \
        bf16x8 vf0[4], vf1[4];                                                   \
        _Pragma("unroll") for (int S = 0; S < 4; ++S) {                          \
            vf0[S] = *(const bf16x8*)&(Vtt)[(S * 2 + 0) * 512 + l8];             \
            vf1[S] = *(const bf16x8*)&(Vtt)[(S * 2 + 1) * 512 + l8];             \
        }                                                                        \
        __builtin_amdgcn_s_setprio(1);                                           \
        _Pragma("unroll") for (int S = 0; S < 4; ++S) {                          \
            const int b0 = (S >> 1) * 8 + (S & 1) * 4;                           \
            unsigned w0 = own[b0 + 0], w2 = own[b0 + 2];                         \
            unsigned w1 = own[b0 + 1], w3 = own[b0 + 3];                         \
            asm("v_permlane32_swap_b32 %0, %1" : "+v"(w0), "+v"(w2));            \
            asm("v_permlane32_swap_b32 %0, %1" : "+v"(w1), "+v"(w3));            \
            union { unsigned u[4]; bf16x8 v; } pb;                               \
            pb.u[0] = w0; pb.u[1] = w1; pb.u[2] = w2; pb.u[3] = w3;              \
            of0 = MFMA32(vf0[S], pb.v, of0);                                     \
            of1 = MFMA32(vf1[S], pb.v, of1);                                     \
        }                                                                        \
        __builtin_amdgcn_s_setprio(0);                                           \
    } while (0)

#define ACOMPUTE2(cur)                                                           \
    do {                                                                         \
        const bf16_t* KtA = kvp + (cur) * 16384;                                 \
        const bf16_t* VtA = KtA + 4096;                                          \
        const bf16_t* KtB = KtA + 8192;                                          \
        const bf16_t* VtB = KtA + 12288;                                         \
        f32x16 scA0, scA1;                                                       \
        ATILE_QK(KtA, scA0, scA1);                                               \
        unsigned ownA[16];                                                       \
        ATILE_SM(scA0, scA1, ownA);                                              \
        f32x16 scB0, scB1;                                                       \
        ATILE_QK(KtB, scB0, scB1);                                               \
        ATILE_PV(VtA, ownA);                                                     \
        unsigned ownB[16];                                                       \
        ATILE_SM(scB0, scB1, ownB);                                              \
        ATILE_PV(VtB, ownB);                                                     \
    } while (0)

    // prologue: both slots staged (pairs 0,1), publish slot 0
    ASTAGE2(0, 0);
    ASTAGE2(1, 1);
    asm volatile("s_waitcnt vmcnt(4)" ::: "memory");
    __builtin_amdgcn_s_barrier();

    for (int p = 0; p < 6; ++p) {
        const int cur = p & 1;
        ACOMPUTE2(cur);
        asm volatile("s_waitcnt lgkmcnt(0)" ::: "memory");  // my reads of slot cur done
        __builtin_amdgcn_s_barrier();                        // all waves done: cur free
        ASTAGE2(cur, p + 2);                                 // refill cur for pair p+2
        asm volatile("s_waitcnt vmcnt(4)" ::: "memory");     // stage(p+1) landed
        __builtin_amdgcn_s_barrier();                        // publish slot cur^1
    }
    // tail: pairs 6, 7
    ACOMPUTE2(0);
    asm volatile("s_waitcnt lgkmcnt(0)" ::: "memory");
    __builtin_amdgcn_s_barrier();
    asm volatile("s_waitcnt vmcnt(0)" ::: "memory");         // stage(7) landed
    __builtin_amdgcn_s_barrier();
    ACOMPUTE2(1);
#undef ASTAGE2
#undef ACOMPUTE2
#undef ATILE_QK
#undef ATILE_SM
#undef ATILE_PV

    // ---- all kv reads retired before olds overwrites the staging space ----
    asm volatile("s_waitcnt lgkmcnt(0)" ::: "memory");
    __builtin_amdgcn_s_barrier();

    // epilogue: deferred lsum tree + normalize + XOR-swizzled transpose + store
#pragma unroll
    for (int st = 8; st >= 1; st >>= 1)
#pragma unroll
        for (int r = 0; r < 8; ++r)
            if (r < st) sacc[r] += sacc[r + st];
    float ltot = sacc[0] + __shfl_xor(sacc[0], 32);
    float inv = 1.f / ltot;
    float* ol = (float*)asmem + (unsigned)w * 2048u;   // per-wave 8KB carve (8x8KB=64KB)
#pragma unroll
    for (int r = 0; r < 16; ++r) {
        int d = (r & 3) + 8 * (r >> 2) + 4 * hi;
        int d2 = 32 + d;
        ol[d * 32 + (ln ^ (d & 31))]    = of0[r] * inv;
        ol[d2 * 32 + (ln ^ (d2 & 31))]  = of1[r] * inv;
    }
    const unsigned obase = (unsigned)(b * 1024 + qw * 32) * 1024u + h * 64 + l;
#pragma unroll 8
    for (int qq = 0; qq < 32; ++qq)
        out[obase + qq * 1024u] = ol[l * 32 + (qq ^ (l & 31))];
}

extern "C" void kernel_launch(void* const* d_in, const int* in_sizes, int n_in,
                              void* d_out, int out_size, void* d_ws, size_t ws_size,
                              hipStream_t stream) {
    const float* x  = (const float*)d_in[0];
    const float* qw = (const float*)d_in[1];
    const float* kw = (const float*)d_in[2];
    const float* vw = (const float*)d_in[3];
    float* out = (float*)d_out;
    char* ws = (char*)d_ws;
    if (ws_size < 67633152u) return;

    bf16_t* xb = (bf16_t*)(ws + XB_OFF);
    bf16_t* wT = (bf16_t*)(ws + WT_OFF);
    bf16_t* Qb = (bf16_t*)(ws + Q_OFF);
    bf16_t* Kb = (bf16_t*)(ws + K_OFF);
    bf16_t* Vt = (bf16_t*)(ws + VT_OFF);

    cast_kernel<<<8448, 256, 0, stream>>>((const float4*)x, (bf16x4*)xb, qw, kw, vw, wT);
    proj_kernel<<<768, 256, 0, stream>>>(xb, wT, Qb, Kb, Vt);
    attn_kernel<<<512, 512, 0, stream>>>(Qb, Kb, Vt, out);
}

// Round 24
// 100.608 us; speedup vs baseline: 1.1760x; 1.0263x over previous
//
#include <hip/hip_runtime.h>

typedef __bf16 bf16_t;
typedef __attribute__((ext_vector_type(2))) __bf16 bf16x2;
typedef __attribute__((ext_vector_type(4))) __bf16 bf16x4;
typedef __attribute__((ext_vector_type(8))) __bf16 bf16x8;
typedef __attribute__((ext_vector_type(4))) float f32x4;
typedef __attribute__((ext_vector_type(16))) float f32x16;

#define MFMA16(a, b, c) __builtin_amdgcn_mfma_f32_16x16x32_bf16((a), (b), (c), 0, 0, 0)
#define MFMA32(a, b, c) __builtin_amdgcn_mfma_f32_32x32x16_bf16((a), (b), (c), 0, 0, 0)
#define AS1 __attribute__((address_space(1)))
#define AS3 __attribute__((address_space(3)))

// Problem: B=8 S=1024 D=768 H=16 Dh=64 OD=1024, M = B*S = 8192
static constexpr unsigned XB_OFF = 0u;                          // x bf16 row-major: 12,582,912
static constexpr unsigned WT_OFF = 12582912u;                   // wT bf16 (3,1024,768): 4,718,592
static constexpr unsigned Q_OFF  = WT_OFF + 4718592u;           // Qf bf16: 16,777,216
static constexpr unsigned K_OFF  = Q_OFF + 16777216u;
static constexpr unsigned VT_OFF = K_OFF + 16777216u;           // end = 67,633,152

// ---------------- merged cast kernel (r23 exact) ----------------
__global__ __launch_bounds__(256) void cast_kernel(const float4* __restrict__ x4,
                                                   bf16x4* __restrict__ out4,
                                                   const float* __restrict__ qw,
                                                   const float* __restrict__ kw,
                                                   const float* __restrict__ vw,
                                                   bf16_t* __restrict__ wT) {
    if (blockIdx.x < 6144u) {
        unsigned i = blockIdx.x * 256u + threadIdx.x;
        float4 v = x4[i];
        bf16x4 o;
        o[0] = (bf16_t)v.x; o[1] = (bf16_t)v.y; o[2] = (bf16_t)v.z; o[3] = (bf16_t)v.w;
        out4[i] = o;
    } else {
        unsigned t = (blockIdx.x - 6144u) * 256u + threadIdx.x;
        unsigned w  = t / 196608u;
        unsigned r  = t % 196608u;
        unsigned n  = r % 1024u;
        unsigned k4 = r / 1024u;
        const float* src = (w == 0u) ? qw : (w == 1u) ? kw : vw;
        float s = (w == 0u) ? 0.18033688011112043f : 1.0f;   // 0.125*log2(e) folded for exp2
        bf16x4 o;
#pragma unroll
        for (int i = 0; i < 4; ++i) o[i] = (bf16_t)(src[(k4 * 4u + i) * 1024u + n] * s);
        *(bf16x4*)&wT[(w * 1024u + n) * 768u + k4 * 4u] = o;
    }
}

// ---------------- fused QKV projection GEMM, BM=128 / BK=64 ------------------
// Per-block LDS halves (2 slots x (16KB A + 16KB B) = 64KB) -> 2 blocks/CU with
// grid 1536 = EXACTLY 3 generations (r23's 768 blocks = 1.5 gens, ~25% tail).
// Per-wave density preserved: 64x64 output, 2 K-steps -> 32 MFMA/phase. Proven
// two-barrier 2-slot ledger (r18-attn): DSREAD -> lgkm(0) -> bar -> STAGE(same
// slot, p+2) -> MFMA -> vmcnt(8) -> bar. Swizzle: 128B row, 8x16B granules,
// read gran (kk*4+hi)^(lo&7), source pre-swizzled (t&7)^((t>>3)&7) (rule 21).
__global__ __launch_bounds__(256, 2) void proj_kernel(const bf16_t* __restrict__ xb,
                                                      const bf16_t* __restrict__ wT,
                                                      bf16_t* __restrict__ q,
                                                      bf16_t* __restrict__ k,
                                                      bf16_t* __restrict__ vt) {
    __shared__ __align__(16) char smem[65536];          // As[2] 32KB | Bs[2] 32KB
    bf16_t* Asp = (bf16_t*)smem;                        // 2 slots x 8192 elems
    bf16_t* Bsp = (bf16_t*)(smem + 32768);              // 2 slots x 8192 elems
    const int id = blockIdx.x;
    const int work = (id & 7) * 192 + (id >> 3);        // bijective, 1536 = 8*192
    const int nb = work & 7, mb = (work >> 3) & 63, wsel = work >> 9;
    const int t = threadIdx.x;
    const int w = t >> 6, l = t & 63;
    const int lo = l & 15, hi = l >> 4;
    const int wm = w >> 1, wn = w & 1;                  // 2x2 waves; per-wave 64x64
    const bf16_t* abase = xb + mb * 128 * 768;
    const bf16_t* bbase = wT + wsel * (1024 * 768) + nb * 128 * 768;
    // staging: issue g covers row g*32 + (t>>3); LDS granule t&7 (16B); source
    // granule pre-swizzled (t&7)^((t>>3)&7)  [row&7 == (t>>3)&7]
    const int srow = t >> 3;
    const int gsrc = ((t & 7) ^ ((t >> 3) & 7)) * 8;

#define STAGE(slot, p)                                                              \
    do {                                                                            \
        const int ko_ = (p) * 64 + gsrc;                                            \
        _Pragma("unroll")                                                           \
        for (int g_ = 0; g_ < 4; ++g_) {                                            \
            __builtin_amdgcn_global_load_lds(                                       \
                (const AS1 void*)(abase + (g_ * 32 + srow) * 768 + ko_),            \
                (AS3 void*)(Asp + (slot) * 8192 + g_ * 2048 + t * 8), 16, 0, 0);    \
            __builtin_amdgcn_global_load_lds(                                       \
                (const AS1 void*)(bbase + (g_ * 32 + srow) * 768 + ko_),            \
                (AS3 void*)(Bsp + (slot) * 8192 + g_ * 2048 + t * 8), 16, 0, 0);    \
        }                                                                           \
    } while (0)

    bf16x8 af[2][4], bfr[2][4];
#define DSREAD(slotv)                                                             \
    do {                                                                          \
        const bf16_t* Ab_ = Asp + (slotv) * 8192;                                 \
        const bf16_t* Bb_ = Bsp + (slotv) * 8192;                                 \
        _Pragma("unroll") for (int kk_ = 0; kk_ < 2; ++kk_)                       \
        _Pragma("unroll") for (int m_ = 0; m_ < 4; ++m_) {                        \
            const int gr_ = ((kk_ * 4 + hi) ^ (lo & 7)) << 3;                     \
            af[kk_][m_]  = *(const bf16x8*)&Ab_[(wm * 64 + m_ * 16 + lo) * 64 + gr_]; \
            bfr[kk_][m_] = *(const bf16x8*)&Bb_[(wn * 64 + m_ * 16 + lo) * 64 + gr_]; \
        }                                                                         \
    } while (0)

#define DOMFMA()                                                                  \
    do {                                                                          \
        __builtin_amdgcn_s_setprio(1);                                            \
        _Pragma("unroll") for (int kk_ = 0; kk_ < 2; ++kk_)                       \
        _Pragma("unroll") for (int m_ = 0; m_ < 4; ++m_)                          \
        _Pragma("unroll") for (int n_ = 0; n_ < 4; ++n_)                          \
            acc[m_][n_] = MFMA16(af[kk_][m_], bfr[kk_][n_], acc[m_][n_]);         \
        __builtin_amdgcn_s_setprio(0);                                            \
    } while (0)

    f32x4 acc[4][4];
#pragma unroll
    for (int m = 0; m < 4; ++m)
#pragma unroll
        for (int n = 0; n < 4; ++n)
#pragma unroll
            for (int i = 0; i < 4; ++i) acc[m][n][i] = 0.f;

    // prologue: both slots staged (K-pairs 0,1), publish slot 0
    STAGE(0, 0);
    STAGE(1, 1);
    asm volatile("s_waitcnt vmcnt(8)" ::: "memory");
    __builtin_amdgcn_s_barrier();

    for (int p = 0; p < 10; ++p) {
        const int slot = p & 1;
        DSREAD(slot);                                      // tile p published
        asm volatile("s_waitcnt lgkmcnt(0)" ::: "memory"); // my reads of slot done
        __builtin_amdgcn_s_barrier();                      // all waves done: slot free
        STAGE(slot, p + 2);                                // refill same slot for p+2
        DOMFMA();                                          // compute from registers
        asm volatile("s_waitcnt vmcnt(8)" ::: "memory");   // stage(p+1) landed
        __builtin_amdgcn_s_barrier();                      // publish tile p+1
    }
    // tail: p = 10, 11 (no more stages; counted drain 8 -> 0)
    DSREAD(0);
    DOMFMA();
    asm volatile("s_waitcnt vmcnt(0)" ::: "memory");       // stage(11) landed
    __builtin_amdgcn_s_barrier();
    DSREAD(1);
    DOMFMA();
#undef STAGE
#undef DSREAD
#undef DOMFMA

    // ---- epilogue: LDS transpose -> 8 coalesced 1KB chunk stores per wave ----
    // Derivation (BM=128): ss = (mb&7)*128 + wm*64 + m*16 + hi*4 + r;
    // dd = n*16 + lo; bb = mb>>3; hh = nb*2 + wn (wave-constant).
    // Q: chunk = qt*4+s, qt=(mb&7)*4+wm*2+(m>>1), s=n -> per-wave c=(m>>1)*4+n.
    // K: chunk = kt*8+s*2+h2, kt=(mb&7)*2+wm, h2=m>>1 -> c=(m>>1)*4+n.
    // V: chunk = kt*8+S*2+h, S=m, h=n>>1 -> c=m*2+(n>>1).
    asm volatile("s_waitcnt lgkmcnt(0)" ::: "memory");
    __builtin_amdgcn_s_barrier();            // all waves past final DSREAD; LDS free
    bf16_t* ep = (bf16_t*)(smem + (unsigned)w * 8192u);    // per-wave 8KB carve
    if (wsel != 2) {
        const int lA = ((lo >> 3) & 1) * 32 + hi * 4;
#pragma unroll
        for (int m = 0; m < 4; ++m)
#pragma unroll
            for (int n = 0; n < 4; ++n)
#pragma unroll
                for (int r = 0; r < 4; ++r)
                    ep[((m >> 1) * 4 + n) * 512 + (lA + (m & 1) * 16 + r) * 8 + (lo & 7)] =
                        (bf16_t)acc[m][n][r];
    } else {
#pragma unroll
        for (int m = 0; m < 4; ++m)
#pragma unroll
            for (int n = 0; n < 4; ++n)
#pragma unroll
                for (int r = 0; r < 4; ++r) {
                    const int sr = hi * 4 + r;   // ss&15
                    ep[(m * 2 + (n >> 1)) * 512
                       + ((sr >> 3) & 1) * 256 + ((n & 1) * 16 + lo) * 8 + (sr & 7)] =
                        (bf16_t)acc[m][n][r];
                }
    }
    asm volatile("s_waitcnt lgkmcnt(0)" ::: "memory");
    __builtin_amdgcn_sched_barrier(0);       // rule #18: pin reads after the wait
    const unsigned headoff = (unsigned)((mb >> 3) * 16 + nb * 2 + wn) << 16;
    bf16_t* dst = (wsel == 0) ? q : (wsel == 1) ? k : vt;
#pragma unroll
    for (int c = 0; c < 8; ++c) {
        unsigned gchunk;
        if (wsel == 0)
            gchunk = (unsigned)((((mb & 7) * 4 + wm * 2 + (c >> 2)) * 4) + (c & 3));
        else if (wsel == 1)
            gchunk = (unsigned)((((mb & 7) * 2 + wm) * 8) + (c & 3) * 2 + (c >> 2));
        else
            gchunk = (unsigned)((((mb & 7) * 2 + wm) * 8) + (c >> 1) * 2 + (c & 1));
        *(bf16x8*)&dst[headoff + gchunk * 512u + l * 8] = *(const bf16x8*)&ep[c * 512 + l * 8];
    }
}

// ---------------- flash attention (r18/r23 exact — best measured, 48.4us) ----
__global__ __launch_bounds__(512) void attn_kernel(const bf16_t* __restrict__ Q,
                                                   const bf16_t* __restrict__ K,
                                                   const bf16_t* __restrict__ Vt,
                                                   float* __restrict__ out) {
    __shared__ __align__(16) char asmem[65536];    // kv[2][2 tiles x 8192]; reused as olds
    bf16_t* kvp = (bf16_t*)asmem;
    const int w = threadIdx.x >> 6, l = threadIdx.x & 63;   // w: 0..7
    const int hb = blockIdx.x & 127;             // head: fixes XCD by hb%8
    const int qblk = blockIdx.x >> 7;            // 0..3
    const int qw = qblk * 8 + w;                 // q-tile 0..31 within head
    const int b = hb >> 4, h = hb & 15;
    const int ln = l & 31, hi = l >> 5;
    const unsigned bh = (unsigned)hb << 16;
    const bf16_t* Qh = Q + bh;
    const bf16_t* Kh = K + bh;
    const bf16_t* Vh = Vt + bh;
    const int l8 = l * 8;

#define ASTAGE2(slot, pair)                                                      \
    do {                                                                         \
        _Pragma("unroll")                                                        \
        for (int tt = 0; tt < 2; ++tt) {                                         \
            const bf16_t* ks_ = Kh + ((pair) * 2 + tt) * 4096;                   \
            const bf16_t* vs_ = Vh + ((pair) * 2 + tt) * 4096;                   \
            bf16_t* dst_ = kvp + (slot) * 16384 + tt * 8192;                     \
            __builtin_amdgcn_global_load_lds(                                    \
                (const AS1 void*)(ks_ + w * 512 + l8),                           \
                (AS3 void*)(dst_ + w * 512), 16, 0, 0);                          \
            __builtin_amdgcn_global_load_lds(                                    \
                (const AS1 void*)(vs_ + w * 512 + l8),                           \
                (AS3 void*)(dst_ + 4096 + w * 512), 16, 0, 0);                   \
        }                                                                        \
    } while (0)

    bf16x8 qf[4];
#pragma unroll
    for (int s = 0; s < 4; ++s)
        qf[s] = *(const bf16x8*)&Qh[(qw * 4 + s) * 512 + l8];

    f32x16 of0, of1;
#pragma unroll
    for (int r = 0; r < 16; ++r) { of0[r] = 0.f; of1[r] = 0.f; }
    float sacc[16];
#pragma unroll
    for (int r = 0; r < 16; ++r) sacc[r] = 0.f;

#define ATILE_QK(Kt, sc0, sc1)                                                   \
    do {                                                                         \
        _Pragma("unroll") for (int r = 0; r < 16; ++r) { sc0[r] = 0.f; sc1[r] = 0.f; } \
        __builtin_amdgcn_s_setprio(1);                                           \
        _Pragma("unroll") for (int s = 0; s < 4; ++s) {                          \
            bf16x8 k0 = *(const bf16x8*)&(Kt)[(s * 2 + 0) * 512 + l8];           \
            bf16x8 k1 = *(const bf16x8*)&(Kt)[(s * 2 + 1) * 512 + l8];           \
            sc0 = MFMA32(k0, qf[s], sc0);                                        \
            sc1 = MFMA32(k1, qf[s], sc1);                                        \
        }                                                                        \
        __builtin_amdgcn_s_setprio(0);                                           \
    } while (0)

#define ATILE_SM(sc0, sc1, own)                                                  \
    do {                                                                         \
        float p0[16], p1[16];                                                    \
        _Pragma("unroll") for (int r = 0; r < 16; ++r) {                         \
            p0[r] = __builtin_amdgcn_exp2f(sc0[r]);                              \
            p1[r] = __builtin_amdgcn_exp2f(sc1[r]);                              \
        }                                                                        \
        _Pragma("unroll") for (int r = 0; r < 16; ++r) sacc[r] += p0[r] + p1[r]; \
        _Pragma("unroll") for (int t2 = 0; t2 < 8; ++t2) {                       \
            bf16x2 v0; v0[0] = (bf16_t)p0[2 * t2]; v0[1] = (bf16_t)p0[2 * t2 + 1]; \
            bf16x2 v1; v1[0] = (bf16_t)p1[2 * t2]; v1[1] = (bf16_t)p1[2 * t2 + 1]; \
            own[t2]     = __builtin_bit_cast(unsigned, v0);                      \
            own[8 + t2] = __builtin_bit_cast(unsigned, v1);                      \
        }                                                                        \
    } while (0)

#define ATILE_PV(Vtt, own)                                                       \
    do {                                                                         \
        bf16x8 vf0[4], vf1[4];                                                   \
        _Pragma("unroll") for (int S = 0; S < 4; ++S) {                          \
            vf0[S] = *(const bf16x8*)&(Vtt)[(S * 2 + 0) * 512 + l8];             \
            vf1[S] = *(const bf16x8*)&(Vtt)[(S * 2 + 1) * 512 + l8];             \
        }                                                                        \
        __builtin_amdgcn_s_setprio(1);                                           \
        _Pragma("unroll") for (int S = 0; S < 4; ++S) {                          \
            const int b0 = (S >> 1) * 8 + (S & 1) * 4;                           \
            unsigned w0 = own[b0 + 0], w2 = own[b0 + 2];                         \
            unsigned w1 = own[b0 + 1], w3 = own[b0 + 3];                         \
            asm("v_permlane32_swap_b32 %0, %1" : "+v"(w0), "+v"(w2));            \
            asm("v_permlane32_swap_b32 %0, %1" : "+v"(w1), "+v"(w3));            \
            union { unsigned u[4]; bf16x8 v; } pb;                               \
            pb.u[0] = w0; pb.u[1] = w1; pb.u[2] = w2; pb.u[3] = w3;              \
            of0 = MFMA32(vf0[S], pb.v, of0);                                     \
            of1 = MFMA32(vf1[S], pb.v, of1);                                     \
        }                                                                        \
        __builtin_amdgcn_s_setprio(0);                                           \
    } while (0)

#define ACOMPUTE2(cur)                                                           \
    do {                                                                         \
        const bf16_t* KtA = kvp + (cur) * 16384;                                 \
        const bf16_t* VtA = KtA + 4096;                                          \
        const bf16_t* KtB = KtA + 8192;                                          \
        const bf16_t* VtB = KtA + 12288;                                         \
        f32x16 scA0, scA1;                                                       \
        ATILE_QK(KtA, scA0, scA1);                                               \
        unsigned ownA[16];                                                       \
        ATILE_SM(scA0, scA1, ownA);                                              \
        f32x16 scB0, scB1;                                                       \
        ATILE_QK(KtB, scB0, scB1);                                               \
        ATILE_PV(VtA, ownA);                                                     \
        unsigned ownB[16];                                                       \
        ATILE_SM(scB0, scB1, ownB);                                              \
        ATILE_PV(VtB, ownB);                                                     \
    } while (0)

    // prologue: both slots staged (pairs 0,1), publish slot 0
    ASTAGE2(0, 0);
    ASTAGE2(1, 1);
    asm volatile("s_waitcnt vmcnt(4)" ::: "memory");
    __builtin_amdgcn_s_barrier();

    for (int p = 0; p < 6; ++p) {
        const int cur = p & 1;
        ACOMPUTE2(cur);
        asm volatile("s_waitcnt lgkmcnt(0)" ::: "memory");  // my reads of slot cur done
        __builtin_amdgcn_s_barrier();                        // all waves done: cur free
        ASTAGE2(cur, p + 2);                                 // refill cur for pair p+2
        asm volatile("s_waitcnt vmcnt(4)" ::: "memory");     // stage(p+1) landed
        __builtin_amdgcn_s_barrier();                        // publish slot cur^1
    }
    // tail: pairs 6, 7
    ACOMPUTE2(0);
    asm volatile("s_waitcnt lgkmcnt(0)" ::: "memory");
    __builtin_amdgcn_s_barrier();
    asm volatile("s_waitcnt vmcnt(0)" ::: "memory");         // stage(7) landed
    __builtin_amdgcn_s_barrier();
    ACOMPUTE2(1);
#undef ASTAGE2
#undef ACOMPUTE2
#undef ATILE_QK
#undef ATILE_SM
#undef ATILE_PV

    // ---- all kv reads retired before olds overwrites the staging space ----
    asm volatile("s_waitcnt lgkmcnt(0)" ::: "memory");
    __builtin_amdgcn_s_barrier();

    // epilogue: deferred lsum tree + normalize + XOR-swizzled transpose + store
#pragma unroll
    for (int st = 8; st >= 1; st >>= 1)
#pragma unroll
        for (int r = 0; r < 8; ++r)
            if (r < st) sacc[r] += sacc[r + st];
    float ltot = sacc[0] + __shfl_xor(sacc[0], 32);
    float inv = 1.f / ltot;
    float* ol = (float*)asmem + (unsigned)w * 2048u;   // per-wave 8KB carve (8x8KB=64KB)
#pragma unroll
    for (int r = 0; r < 16; ++r) {
        int d = (r & 3) + 8 * (r >> 2) + 4 * hi;
        int d2 = 32 + d;
        ol[d * 32 + (ln ^ (d & 31))]    = of0[r] * inv;
        ol[d2 * 32 + (ln ^ (d2 & 31))]  = of1[r] * inv;
    }
    const unsigned obase = (unsigned)(b * 1024 + qw * 32) * 1024u + h * 64 + l;
#pragma unroll 8
    for (int qq = 0; qq < 32; ++qq)
        out[obase + qq * 1024u] = ol[l * 32 + (qq ^ (l & 31))];
}

extern "C" void kernel_launch(void* const* d_in, const int* in_sizes, int n_in,
                              void* d_out, int out_size, void* d_ws, size_t ws_size,
                              hipStream_t stream) {
    const float* x  = (const float*)d_in[0];
    const float* qw = (const float*)d_in[1];
    const float* kw = (const float*)d_in[2];
    const float* vw = (const float*)d_in[3];
    float* out = (float*)d_out;
    char* ws = (char*)d_ws;
    if (ws_size < 67633152u) return;

    bf16_t* xb = (bf16_t*)(ws + XB_OFF);
    bf16_t* wT = (bf16_t*)(ws + WT_OFF);
    bf16_t* Qb = (bf16_t*)(ws + Q_OFF);
    bf16_t* Kb = (bf16_t*)(ws + K_OFF);
    bf16_t* Vt = (bf16_t*)(ws + VT_OFF);

    cast_kernel<<<8448, 256, 0, stream>>>((const float4*)x, (bf16x4*)xb, qw, kw, vw, wT);
    proj_kernel<<<1536, 256, 0, stream>>>(xb, wT, Qb, Kb, Vt);
    attn_kernel<<<512, 512, 0, stream>>>(Qb, Kb, Vt, out);
}

// Round 25
// 100.399 us; speedup vs baseline: 1.1784x; 1.0021x over previous
//
#include <hip/hip_runtime.h>

typedef __bf16 bf16_t;
typedef __attribute__((ext_vector_type(2))) __bf16 bf16x2;
typedef __attribute__((ext_vector_type(4))) __bf16 bf16x4;
typedef __attribute__((ext_vector_type(8))) __bf16 bf16x8;
typedef __attribute__((ext_vector_type(4))) float f32x4;
typedef __attribute__((ext_vector_type(16))) float f32x16;

#define MFMA16(a, b, c) __builtin_amdgcn_mfma_f32_16x16x32_bf16((a), (b), (c), 0, 0, 0)
#define MFMA32(a, b, c) __builtin_amdgcn_mfma_f32_32x32x16_bf16((a), (b), (c), 0, 0, 0)
#define AS1 __attribute__((address_space(1)))
#define AS3 __attribute__((address_space(3)))

// Problem: B=8 S=1024 D=768 H=16 Dh=64 OD=1024, M = B*S = 8192
static constexpr unsigned XB_OFF = 0u;                          // x bf16 row-major: 12,582,912
static constexpr unsigned WT_OFF = 12582912u;                   // wT bf16 (3,1024,768): 4,718,592
static constexpr unsigned Q_OFF  = WT_OFF + 4718592u;           // Qf bf16: 16,777,216
static constexpr unsigned K_OFF  = Q_OFF + 16777216u;
static constexpr unsigned VT_OFF = K_OFF + 16777216u;           // end = 67,633,152

// ---------------- merged cast kernel (r24 exact) ----------------
__global__ __launch_bounds__(256) void cast_kernel(const float4* __restrict__ x4,
                                                   bf16x4* __restrict__ out4,
                                                   const float* __restrict__ qw,
                                                   const float* __restrict__ kw,
                                                   const float* __restrict__ vw,
                                                   bf16_t* __restrict__ wT) {
    if (blockIdx.x < 6144u) {
        unsigned i = blockIdx.x * 256u + threadIdx.x;
        float4 v = x4[i];
        bf16x4 o;
        o[0] = (bf16_t)v.x; o[1] = (bf16_t)v.y; o[2] = (bf16_t)v.z; o[3] = (bf16_t)v.w;
        out4[i] = o;
    } else {
        unsigned t = (blockIdx.x - 6144u) * 256u + threadIdx.x;
        unsigned w  = t / 196608u;
        unsigned r  = t % 196608u;
        unsigned n  = r % 1024u;
        unsigned k4 = r / 1024u;
        const float* src = (w == 0u) ? qw : (w == 1u) ? kw : vw;
        float s = (w == 0u) ? 0.18033688011112043f : 1.0f;   // 0.125*log2(e) folded for exp2
        bf16x4 o;
#pragma unroll
        for (int i = 0; i < 4; ++i) o[i] = (bf16_t)(src[(k4 * 4u + i) * 1024u + n] * s);
        *(bf16x4*)&wT[(w * 1024u + n) * 768u + k4 * 4u] = o;
    }
}

// ---------------- fused QKV projection GEMM, BM=128 / BK=64 (r24 exact) ------
__global__ __launch_bounds__(256, 2) void proj_kernel(const bf16_t* __restrict__ xb,
                                                      const bf16_t* __restrict__ wT,
                                                      bf16_t* __restrict__ q,
                                                      bf16_t* __restrict__ k,
                                                      bf16_t* __restrict__ vt) {
    __shared__ __align__(16) char smem[65536];          // As[2] 32KB | Bs[2] 32KB
    bf16_t* Asp = (bf16_t*)smem;                        // 2 slots x 8192 elems
    bf16_t* Bsp = (bf16_t*)(smem + 32768);              // 2 slots x 8192 elems
    const int id = blockIdx.x;
    const int work = (id & 7) * 192 + (id >> 3);        // bijective, 1536 = 8*192
    const int nb = work & 7, mb = (work >> 3) & 63, wsel = work >> 9;
    const int t = threadIdx.x;
    const int w = t >> 6, l = t & 63;
    const int lo = l & 15, hi = l >> 4;
    const int wm = w >> 1, wn = w & 1;                  // 2x2 waves; per-wave 64x64
    const bf16_t* abase = xb + mb * 128 * 768;
    const bf16_t* bbase = wT + wsel * (1024 * 768) + nb * 128 * 768;
    const int srow = t >> 3;
    const int gsrc = ((t & 7) ^ ((t >> 3) & 7)) * 8;

#define STAGE(slot, p)                                                              \
    do {                                                                            \
        const int ko_ = (p) * 64 + gsrc;                                            \
        _Pragma("unroll")                                                           \
        for (int g_ = 0; g_ < 4; ++g_) {                                            \
            __builtin_amdgcn_global_load_lds(                                       \
                (const AS1 void*)(abase + (g_ * 32 + srow) * 768 + ko_),            \
                (AS3 void*)(Asp + (slot) * 8192 + g_ * 2048 + t * 8), 16, 0, 0);    \
            __builtin_amdgcn_global_load_lds(                                       \
                (const AS1 void*)(bbase + (g_ * 32 + srow) * 768 + ko_),            \
                (AS3 void*)(Bsp + (slot) * 8192 + g_ * 2048 + t * 8), 16, 0, 0);    \
        }                                                                           \
    } while (0)

    bf16x8 af[2][4], bfr[2][4];
#define DSREAD(slotv)                                                             \
    do {                                                                          \
        const bf16_t* Ab_ = Asp + (slotv) * 8192;                                 \
        const bf16_t* Bb_ = Bsp + (slotv) * 8192;                                 \
        _Pragma("unroll") for (int kk_ = 0; kk_ < 2; ++kk_)                       \
        _Pragma("unroll") for (int m_ = 0; m_ < 4; ++m_) {                        \
            const int gr_ = ((kk_ * 4 + hi) ^ (lo & 7)) << 3;                     \
            af[kk_][m_]  = *(const bf16x8*)&Ab_[(wm * 64 + m_ * 16 + lo) * 64 + gr_]; \
            bfr[kk_][m_] = *(const bf16x8*)&Bb_[(wn * 64 + m_ * 16 + lo) * 64 + gr_]; \
        }                                                                         \
    } while (0)

#define DOMFMA()                                                                  \
    do {                                                                          \
        __builtin_amdgcn_s_setprio(1);                                            \
        _Pragma("unroll") for (int kk_ = 0; kk_ < 2; ++kk_)                       \
        _Pragma("unroll") for (int m_ = 0; m_ < 4; ++m_)                          \
        _Pragma("unroll") for (int n_ = 0; n_ < 4; ++n_)                          \
            acc[m_][n_] = MFMA16(af[kk_][m_], bfr[kk_][n_], acc[m_][n_]);         \
        __builtin_amdgcn_s_setprio(0);                                            \
    } while (0)

    f32x4 acc[4][4];
#pragma unroll
    for (int m = 0; m < 4; ++m)
#pragma unroll
        for (int n = 0; n < 4; ++n)
#pragma unroll
            for (int i = 0; i < 4; ++i) acc[m][n][i] = 0.f;

    STAGE(0, 0);
    STAGE(1, 1);
    asm volatile("s_waitcnt vmcnt(8)" ::: "memory");
    __builtin_amdgcn_s_barrier();

    for (int p = 0; p < 10; ++p) {
        const int slot = p & 1;
        DSREAD(slot);
        asm volatile("s_waitcnt lgkmcnt(0)" ::: "memory");
        __builtin_amdgcn_s_barrier();
        STAGE(slot, p + 2);
        DOMFMA();
        asm volatile("s_waitcnt vmcnt(8)" ::: "memory");
        __builtin_amdgcn_s_barrier();
    }
    DSREAD(0);
    DOMFMA();
    asm volatile("s_waitcnt vmcnt(0)" ::: "memory");
    __builtin_amdgcn_s_barrier();
    DSREAD(1);
    DOMFMA();
#undef STAGE
#undef DSREAD
#undef DOMFMA

    asm volatile("s_waitcnt lgkmcnt(0)" ::: "memory");
    __builtin_amdgcn_s_barrier();
    bf16_t* ep = (bf16_t*)(smem + (unsigned)w * 8192u);    // per-wave 8KB carve
    if (wsel != 2) {
        const int lA = ((lo >> 3) & 1) * 32 + hi * 4;
#pragma unroll
        for (int m = 0; m < 4; ++m)
#pragma unroll
            for (int n = 0; n < 4; ++n)
#pragma unroll
                for (int r = 0; r < 4; ++r)
                    ep[((m >> 1) * 4 + n) * 512 + (lA + (m & 1) * 16 + r) * 8 + (lo & 7)] =
                        (bf16_t)acc[m][n][r];
    } else {
#pragma unroll
        for (int m = 0; m < 4; ++m)
#pragma unroll
            for (int n = 0; n < 4; ++n)
#pragma unroll
                for (int r = 0; r < 4; ++r) {
                    const int sr = hi * 4 + r;   // ss&15
                    ep[(m * 2 + (n >> 1)) * 512
                       + ((sr >> 3) & 1) * 256 + ((n & 1) * 16 + lo) * 8 + (sr & 7)] =
                        (bf16_t)acc[m][n][r];
                }
    }
    asm volatile("s_waitcnt lgkmcnt(0)" ::: "memory");
    __builtin_amdgcn_sched_barrier(0);       // rule #18: pin reads after the wait
    const unsigned headoff = (unsigned)((mb >> 3) * 16 + nb * 2 + wn) << 16;
    bf16_t* dst = (wsel == 0) ? q : (wsel == 1) ? k : vt;
#pragma unroll
    for (int c = 0; c < 8; ++c) {
        unsigned gchunk;
        if (wsel == 0)
            gchunk = (unsigned)((((mb & 7) * 4 + wm * 2 + (c >> 2)) * 4) + (c & 3));
        else if (wsel == 1)
            gchunk = (unsigned)((((mb & 7) * 2 + wm) * 8) + (c & 3) * 2 + (c >> 2));
        else
            gchunk = (unsigned)((((mb & 7) * 2 + wm) * 8) + (c >> 1) * 2 + (c & 1));
        *(bf16x8*)&dst[headoff + gchunk * 512u + l * 8] = *(const bf16x8*)&ep[c * 512 + l * 8];
    }
}

// ---------------- flash attention (r18 structure, setprio REMOVED) -----------
// m190/m191 regime analysis: setprio pays only for independent-wave schedules;
// since r13 attn is 8-wave barrier-lockstep (the m190 null/negative regime), so
// the 32 setprio toggles/wave are pure overhead. Everything else r18-exact.
__global__ __launch_bounds__(512) void attn_kernel(const bf16_t* __restrict__ Q,
                                                   const bf16_t* __restrict__ K,
                                                   const bf16_t* __restrict__ Vt,
                                                   float* __restrict__ out) {
    __shared__ __align__(16) char asmem[65536];    // kv[2][2 tiles x 8192]; reused as olds
    bf16_t* kvp = (bf16_t*)asmem;
    const int w = threadIdx.x >> 6, l = threadIdx.x & 63;   // w: 0..7
    const int hb = blockIdx.x & 127;             // head: fixes XCD by hb%8
    const int qblk = blockIdx.x >> 7;            // 0..3
    const int qw = qblk * 8 + w;                 // q-tile 0..31 within head
    const int b = hb >> 4, h = hb & 15;
    const int ln = l & 31, hi = l >> 5;
    const unsigned bh = (unsigned)hb << 16;
    const bf16_t* Qh = Q + bh;
    const bf16_t* Kh = K + bh;
    const bf16_t* Vh = Vt + bh;
    const int l8 = l * 8;

#define ASTAGE2(slot, pair)                                                      \
    do {                                                                         \
        _Pragma("unroll")                                                        \
        for (int tt = 0; tt < 2; ++tt) {                                         \
            const bf16_t* ks_ = Kh + ((pair) * 2 + tt) * 4096;                   \
            const bf16_t* vs_ = Vh + ((pair) * 2 + tt) * 4096;                   \
            bf16_t* dst_ = kvp + (slot) * 16384 + tt * 8192;                     \
            __builtin_amdgcn_global_load_lds(                                    \
                (const AS1 void*)(ks_ + w * 512 + l8),                           \
                (AS3 void*)(dst_ + w * 512), 16, 0, 0);                          \
            __builtin_amdgcn_global_load_lds(                                    \
                (const AS1 void*)(vs_ + w * 512 + l8),                           \
                (AS3 void*)(dst_ + 4096 + w * 512), 16, 0, 0);                   \
        }                                                                        \
    } while (0)

    bf16x8 qf[4];
#pragma unroll
    for (int s = 0; s < 4; ++s)
        qf[s] = *(const bf16x8*)&Qh[(qw * 4 + s) * 512 + l8];

    f32x16 of0, of1;
#pragma unroll
    for (int r = 0; r < 16; ++r) { of0[r] = 0.f; of1[r] = 0.f; }
    float sacc[16];
#pragma unroll
    for (int r = 0; r < 16; ++r) sacc[r] = 0.f;

#define ATILE_QK(Kt, sc0, sc1)                                                   \
    do {                                                                         \
        _Pragma("unroll") for (int r = 0; r < 16; ++r) { sc0[r] = 0.f; sc1[r] = 0.f; } \
        _Pragma("unroll") for (int s = 0; s < 4; ++s) {                          \
            bf16x8 k0 = *(const bf16x8*)&(Kt)[(s * 2 + 0) * 512 + l8];           \
            bf16x8 k1 = *(const bf16x8*)&(Kt)[(s * 2 + 1) * 512 + l8];           \
            sc0 = MFMA32(k0, qf[s], sc0);                                        \
            sc1 = MFMA32(k1, qf[s], sc1);                                        \
        }                                                                        \
    } while (0)

#define ATILE_SM(sc0, sc1, own)                                                  \
    do {                                                                         \
        float p0[16], p1[16];                                                    \
        _Pragma("unroll") for (int r = 0; r < 16; ++r) {                         \
            p0[r] = __builtin_amdgcn_exp2f(sc0[r]);                              \
            p1[r] = __builtin_amdgcn_exp2f(sc1[r]);                              \
        }                                                                        \
        _Pragma("unroll") for (int r = 0; r < 16; ++r) sacc[r] += p0[r] + p1[r]; \
        _Pragma("unroll") for (int t2 = 0; t2 < 8; ++t2) {                       \
            bf16x2 v0; v0[0] = (bf16_t)p0[2 * t2]; v0[1] = (bf16_t)p0[2 * t2 + 1]; \
            bf16x2 v1; v1[0] = (bf16_t)p1[2 * t2]; v1[1] = (bf16_t)p1[2 * t2 + 1]; \
            own[t2]     = __builtin_bit_cast(unsigned, v0);                      \
            own[8 + t2] = __builtin_bit_cast(unsigned, v1);                      \
        }                                                                        \
    } while (0)

#define ATILE_PV(Vtt, own)                                                       \
    do {                                                                         \
        bf16x8 vf0[4], vf1[4];                                                   \
        _Pragma("unroll") for (int S = 0; S < 4; ++S) {                          \
            vf0[S] = *(const bf16x8*)&(Vtt)[(S * 2 + 0) * 512 + l8];             \
            vf1[S] = *(const bf16x8*)&(Vtt)[(S * 2 + 1) * 512 + l8];             \
        }                                                                        \
        _Pragma("unroll") for (int S = 0; S < 4; ++S) {                          \
            const int b0 = (S >> 1) * 8 + (S & 1) * 4;                           \
            unsigned w0 = own[b0 + 0], w2 = own[b0 + 2];                         \
            unsigned w1 = own[b0 + 1], w3 = own[b0 + 3];                         \
            asm("v_permlane32_swap_b32 %0, %1" : "+v"(w0), "+v"(w2));            \
            asm("v_permlane32_swap_b32 %0, %1" : "+v"(w1), "+v"(w3));            \
            union { unsigned u[4]; bf16x8 v; } pb;                               \
            pb.u[0] = w0; pb.u[1] = w1; pb.u[2] = w2; pb.u[3] = w3;              \
            of0 = MFMA32(vf0[S], pb.v, of0);                                     \
            of1 = MFMA32(vf1[S], pb.v, of1);                                     \
        }                                                                        \
    } while (0)

#define ACOMPUTE2(cur)                                                           \
    do {                                                                         \
        const bf16_t* KtA = kvp + (cur) * 16384;                                 \
        const bf16_t* VtA = KtA + 4096;                                          \
        const bf16_t* KtB = KtA + 8192;                                          \
        const bf16_t* VtB = KtA + 12288;                                         \
        f32x16 scA0, scA1;                                                       \
        ATILE_QK(KtA, scA0, scA1);                                               \
        unsigned ownA[16];                                                       \
        ATILE_SM(scA0, scA1, ownA);                                              \
        f32x16 scB0, scB1;                                                       \
        ATILE_QK(KtB, scB0, scB1);                                               \
        ATILE_PV(VtA, ownA);                                                     \
        unsigned ownB[16];                                                       \
        ATILE_SM(scB0, scB1, ownB);                                              \
        ATILE_PV(VtB, ownB);                                                     \
    } while (0)

    // prologue: both slots staged (pairs 0,1), publish slot 0
    ASTAGE2(0, 0);
    ASTAGE2(1, 1);
    asm volatile("s_waitcnt vmcnt(4)" ::: "memory");
    __builtin_amdgcn_s_barrier();

    for (int p = 0; p < 6; ++p) {
        const int cur = p & 1;
        ACOMPUTE2(cur);
        asm volatile("s_waitcnt lgkmcnt(0)" ::: "memory");  // my reads of slot cur done
        __builtin_amdgcn_s_barrier();                        // all waves done: cur free
        ASTAGE2(cur, p + 2);                                 // refill cur for pair p+2
        asm volatile("s_waitcnt vmcnt(4)" ::: "memory");     // stage(p+1) landed
        __builtin_amdgcn_s_barrier();                        // publish slot cur^1
    }
    // tail: pairs 6, 7
    ACOMPUTE2(0);
    asm volatile("s_waitcnt lgkmcnt(0)" ::: "memory");
    __builtin_amdgcn_s_barrier();
    asm volatile("s_waitcnt vmcnt(0)" ::: "memory");         // stage(7) landed
    __builtin_amdgcn_s_barrier();
    ACOMPUTE2(1);
#undef ASTAGE2
#undef ACOMPUTE2
#undef ATILE_QK
#undef ATILE_SM
#undef ATILE_PV

    // ---- all kv reads retired before olds overwrites the staging space ----
    asm volatile("s_waitcnt lgkmcnt(0)" ::: "memory");
    __builtin_amdgcn_s_barrier();

    // epilogue: deferred lsum tree + normalize + XOR-swizzled transpose + store
#pragma unroll
    for (int st = 8; st >= 1; st >>= 1)
#pragma unroll
        for (int r = 0; r < 8; ++r)
            if (r < st) sacc[r] += sacc[r + st];
    float ltot = sacc[0] + __shfl_xor(sacc[0], 32);
    float inv = 1.f / ltot;
    float* ol = (float*)asmem + (unsigned)w * 2048u;   // per-wave 8KB carve (8x8KB=64KB)
#pragma unroll
    for (int r = 0; r < 16; ++r) {
        int d = (r & 3) + 8 * (r >> 2) + 4 * hi;
        int d2 = 32 + d;
        ol[d * 32 + (ln ^ (d & 31))]    = of0[r] * inv;
        ol[d2 * 32 + (ln ^ (d2 & 31))]  = of1[r] * inv;
    }
    const unsigned obase = (unsigned)(b * 1024 + qw * 32) * 1024u + h * 64 + l;
#pragma unroll 8
    for (int qq = 0; qq < 32; ++qq)
        out[obase + qq * 1024u] = ol[l * 32 + (qq ^ (l & 31))];
}

extern "C" void kernel_launch(void* const* d_in, const int* in_sizes, int n_in,
                              void* d_out, int out_size, void* d_ws, size_t ws_size,
                              hipStream_t stream) {
    const float* x  = (const float*)d_in[0];
    const float* qw = (const float*)d_in[1];
    const float* kw = (const float*)d_in[2];
    const float* vw = (const float*)d_in[3];
    float* out = (float*)d_out;
    char* ws = (char*)d_ws;
    if (ws_size < 67633152u) return;

    bf16_t* xb = (bf16_t*)(ws + XB_OFF);
    bf16_t* wT = (bf16_t*)(ws + WT_OFF);
    bf16_t* Qb = (bf16_t*)(ws + Q_OFF);
    bf16_t* Kb = (bf16_t*)(ws + K_OFF);
    bf16_t* Vt = (bf16_t*)(ws + VT_OFF);

    cast_kernel<<<8448, 256, 0, stream>>>((const float4*)x, (bf16x4*)xb, qw, kw, vw, wT);
    proj_kernel<<<1536, 256, 0, stream>>>(xb, wT, Qb, Kb, Vt);
    attn_kernel<<<512, 512, 0, stream>>>(Qb, Kb, Vt, out);
}